// Round 6
// baseline (1729.738 us; speedup 1.0000x reference)
//
#include <hip/hip_runtime.h>
#include <math.h>

#define SEQ_LEN   720
#define IN_LEN    360
#define PRED_LEN  336
#define CHANNELS  862
#define RANK      32
#define BATCH     256

// ws layout (float offsets)
#define WS_WP    0            // Wp  [360][32]
#define WS_VT    11520        // Vt  [336][32]
#define WS_CVEC  22272        // cvec[336]
#define WS_T     22608        // partial t: [b][kh][c][r] = 2*256*862*32
#define WS_S     14145616     // partial S: [b][kh][c]    = 2*256*862
#define WS_TOTAL 14586960     // floats

// ---------------- single prep kernel (89 blocks) -----------------------------
__global__ __launch_bounds__(256) void k_prep(const float* __restrict__ A,
                                              const float* __restrict__ B,
                                              const float* __restrict__ bias,
                                              float* __restrict__ Wp,
                                              float* __restrict__ Vt,
                                              float* __restrict__ cvec) {
    __shared__ float sbuf[IN_LEN * RANK];            // 46080 B
    int blk = blockIdx.x;
    if (blk < 45) {
        for (int i = threadIdx.x; i < IN_LEN * RANK; i += 256) sbuf[i] = A[i];
        __syncthreads();
        int idx = blk * 256 + threadIdx.x;           // 45*256 == 11520
        int n = idx >> 5, r = idx & 31;
        int step = 2 * n + 1, m = 0;                 // k*(2n+1) mod 1440
        float sum = 0.f;
        for (int k = 0; k < IN_LEN; ++k) {
            float coef = (k == 0) ? 0.05270462766947299f    // 1/sqrt(360)
                                  : 0.07453559924999299f;   // 2/sqrt(720)
            float d = coef * cospif((float)m * (1.0f / 720.0f));
            sum = fmaf(d, sbuf[k * RANK + r], sum);
            m += step; if (m >= 1440) m -= 1440;
        }
        Wp[idx] = sum * 0.0019641855032960957f;      // (1/sqrt2)/360
    } else if (blk < 87) {
        for (int i = threadIdx.x; i < PRED_LEN * RANK; i += 256) {
            int r = i / PRED_LEN, k = i - r * PRED_LEN;
            sbuf[k * RANK + r] = B[i];               // B transposed -> [k][r]
        }
        __syncthreads();
        int idx = (blk - 45) * 256 + threadIdx.x;    // 42*256 == 10752
        int n = idx >> 5, r = idx & 31;
        int step = 2 * n + 1, m = 0;                 // k*(2n+1) mod 1344
        float sum = 0.f;
        for (int k = 0; k < PRED_LEN; ++k) {
            float mk = cospif((float)m * (1.0f / 672.0f));
            if (k == 0) mk *= 0.5f;
            sum = fmaf(mk, sbuf[k * RANK + r], sum);
            m += step; if (m >= 1344) m -= 1344;
        }
        Vt[idx] = sum * (1.0f / 336.0f);
    } else {
        int n = (blk - 87) * 256 + threadIdx.x;
        if (n < PRED_LEN) {
            int step = 2 * n + 1, m = 0;
            float sum = 0.f;
            for (int k = 0; k < PRED_LEN; ++k) {
                float mk = cospif((float)m * (1.0f / 672.0f));
                if (k == 0) mk *= 0.5f;
                sum = fmaf(mk, bias[k], sum);
                m += step; if (m >= 1344) m -= 1344;
            }
            cvec[n] = sum * (1.0f / 336.0f);
        }
    }
}

// ---------------- kernel A: split-K partial t --------------------------------
// grid (4, BATCH): blockIdx.x -> {c-half, k-half}. 256 thr, cpt=2, 16 waves/CU.
// Each block: 180 x-row-pairs over its 431/432-channel half; W-half in LDS.
__global__ __launch_bounds__(256, 4) void k_partial(const float* __restrict__ x,
                                                    const float* __restrict__ Wp,
                                                    float* __restrict__ wsT,
                                                    float* __restrict__ wsS) {
    __shared__ float lw[180 * RANK];                 // 23040 B
    const int tid = threadIdx.x;
    const int ch = blockIdx.x & 1, kh = blockIdx.x >> 1;
    const int b = blockIdx.y;

    {
        const float4* src = (const float4*)(Wp + kh * 180 * RANK);
        float4* dst = (float4*)lw;
        for (int i = tid; i < 180 * RANK / 4; i += 256) dst[i] = src[i];
    }
    __syncthreads();

    const int c0 = 2 * (ch * 216 + tid);
    if (c0 >= CHANNELS) return;                      // no barriers after this

    float acc0[RANK], acc1[RANK];
    #pragma unroll
    for (int r = 0; r < RANK; ++r) { acc0[r] = 0.f; acc1[r] = 0.f; }
    float S0 = 0.f, S1 = 0.f;

    const float* xp = x + (size_t)b * (SEQ_LEN * CHANNELS)
                        + (size_t)kh * (IN_LEN * CHANNELS) + c0;

    float2 na0 = *(const float2*)(xp);
    float2 na1 = *(const float2*)(xp + CHANNELS);

    for (int n = 0; n < 180; ++n) {
        float2 a0 = na0, a1 = na1;
        if (n < 179) {
            na0 = *(const float2*)(xp + 2 * CHANNELS);
            na1 = *(const float2*)(xp + 3 * CHANNELS);
        }
        xp += 2 * CHANNELS;
        float p0 = a0.x + a1.x;
        float p1 = a0.y + a1.y;
        S0 += p0; S1 += p1;
        const float4* w = (const float4*)(lw + n * RANK);
        #pragma unroll
        for (int q = 0; q < 8; ++q) {
            float4 wv = w[q];
            acc0[4*q+0] = fmaf(p0, wv.x, acc0[4*q+0]);
            acc1[4*q+0] = fmaf(p1, wv.x, acc1[4*q+0]);
            acc0[4*q+1] = fmaf(p0, wv.y, acc0[4*q+1]);
            acc1[4*q+1] = fmaf(p1, wv.y, acc1[4*q+1]);
            acc0[4*q+2] = fmaf(p0, wv.z, acc0[4*q+2]);
            acc1[4*q+2] = fmaf(p1, wv.z, acc1[4*q+2]);
            acc0[4*q+3] = fmaf(p0, wv.w, acc0[4*q+3]);
            acc1[4*q+3] = fmaf(p1, wv.w, acc1[4*q+3]);
        }
    }

    // store partials: [b][kh][c][r], 256 B contiguous per thread
    float* tp = wsT + ((size_t)(b * 2 + kh) * CHANNELS + c0) * RANK;
    #pragma unroll
    for (int q = 0; q < 8; ++q) {
        float4 v0 = { acc0[4*q+0], acc0[4*q+1], acc0[4*q+2], acc0[4*q+3] };
        ((float4*)tp)[q] = v0;
        float4 v1 = { acc1[4*q+0], acc1[4*q+1], acc1[4*q+2], acc1[4*q+3] };
        ((float4*)(tp + RANK))[q] = v1;
    }
    wsS[(size_t)(b * 2 + kh) * CHANNELS + c0]     = S0;
    wsS[(size_t)(b * 2 + kh) * CHANNELS + c0 + 1] = S1;
}

// ---------------- kernel B: combine + finalize + phase 2 ---------------------
// grid (4, BATCH): blockIdx.x -> {c-half, n-half}. 256 thr, cpt=2, 16 waves/CU.
__global__ __launch_bounds__(256, 4) void k_final(const float* __restrict__ A,
                                                  const float* __restrict__ Vt,
                                                  const float* __restrict__ cvec,
                                                  const float* __restrict__ wsT,
                                                  const float* __restrict__ wsS,
                                                  float* __restrict__ out) {
    __shared__ float lv[168 * RANK + 168];           // 22176 B
    const int tid = threadIdx.x;
    const int ch = blockIdx.x & 1, nh = blockIdx.x >> 1;
    const int b = blockIdx.y;

    {
        const float4* src = (const float4*)(Vt + nh * 168 * RANK);
        float4* dst = (float4*)lv;
        for (int i = tid; i < 168 * RANK / 4; i += 256) dst[i] = src[i];
        for (int i = tid; i < 168; i += 256) lv[168 * RANK + i] = cvec[nh * 168 + i];
    }
    __syncthreads();

    const int c0 = 2 * (ch * 216 + tid);
    if (c0 >= CHANNELS) return;                      // no barriers after this

    // combine k-halves
    float t0[RANK], t1[RANK];
    const float* pa = wsT + ((size_t)(b * 2 + 0) * CHANNELS + c0) * RANK;
    const float* pb = wsT + ((size_t)(b * 2 + 1) * CHANNELS + c0) * RANK;
    #pragma unroll
    for (int q = 0; q < 8; ++q) {
        float4 u = ((const float4*)pa)[q], v = ((const float4*)pb)[q];
        t0[4*q+0] = u.x + v.x; t0[4*q+1] = u.y + v.y;
        t0[4*q+2] = u.z + v.z; t0[4*q+3] = u.w + v.w;
        float4 u2 = ((const float4*)(pa + RANK))[q], v2 = ((const float4*)(pb + RANK))[q];
        t1[4*q+0] = u2.x + v2.x; t1[4*q+1] = u2.y + v2.y;
        t1[4*q+2] = u2.z + v2.z; t1[4*q+3] = u2.w + v2.w;
    }
    float S0 = wsS[(size_t)(b * 2 + 0) * CHANNELS + c0]
             + wsS[(size_t)(b * 2 + 1) * CHANNELS + c0];
    float S1 = wsS[(size_t)(b * 2 + 0) * CHANNELS + c0 + 1]
             + wsS[(size_t)(b * 2 + 1) * CHANNELS + c0 + 1];

    // finalize: csw[r] = A[0][r]/sqrt(720); t -= (S/360)*csw
    {
        const float k360 = (1.0f / 360.0f) * 0.037267799624996496f;
        float g0 = -S0 * k360, g1 = -S1 * k360;
        #pragma unroll
        for (int q = 0; q < 8; ++q) {
            float4 a4 = ((const float4*)A)[q];       // A[0][0..31], uniform, L2-hot
            t0[4*q+0] = fmaf(g0, a4.x, t0[4*q+0]);
            t1[4*q+0] = fmaf(g1, a4.x, t1[4*q+0]);
            t0[4*q+1] = fmaf(g0, a4.y, t0[4*q+1]);
            t1[4*q+1] = fmaf(g1, a4.y, t1[4*q+1]);
            t0[4*q+2] = fmaf(g0, a4.z, t0[4*q+2]);
            t1[4*q+2] = fmaf(g1, a4.z, t1[4*q+2]);
            t0[4*q+3] = fmaf(g0, a4.w, t0[4*q+3]);
            t1[4*q+3] = fmaf(g1, a4.w, t1[4*q+3]);
        }
    }
    const float mean0 = S0 * (1.0f / 720.0f);
    const float mean1 = S1 * (1.0f / 720.0f);

    // phase 2: this block's 168 output rows
    float* op = out + (size_t)b * (PRED_LEN * CHANNELS)
                    + (size_t)(nh * 168) * CHANNELS + c0;
    for (int nl = 0; nl < 168; ++nl) {
        const float4* vrow = (const float4*)lv + nl * 8;
        float o0a = 0.f, o0b = 0.f, o0c = 0.f, o0d = 0.f;
        float o1a = 0.f, o1b = 0.f, o1c = 0.f, o1d = 0.f;
        #pragma unroll
        for (int q = 0; q < 8; ++q) {
            float4 vv = vrow[q];
            o0a = fmaf(t0[4*q+0], vv.x, o0a);
            o1a = fmaf(t1[4*q+0], vv.x, o1a);
            o0b = fmaf(t0[4*q+1], vv.y, o0b);
            o1b = fmaf(t1[4*q+1], vv.y, o1b);
            o0c = fmaf(t0[4*q+2], vv.z, o0c);
            o1c = fmaf(t1[4*q+2], vv.z, o1c);
            o0d = fmaf(t0[4*q+3], vv.w, o0d);
            o1d = fmaf(t1[4*q+3], vv.w, o1d);
        }
        float cvn = lv[168 * RANK + nl];
        float2 o;
        o.x = (o0a + o0b) + (o0c + o0d) + cvn + mean0;
        o.y = (o1a + o1b) + (o1c + o1d) + cvn + mean1;
        *(float2*)(op) = o;
        op += CHANNELS;
    }
}

// ---------------- fallback single fused kernel (round-2 proven) --------------
__global__ __launch_bounds__(256, 2) void k_fused(const float* __restrict__ x,
                                                  const float* __restrict__ A,
                                                  const float* __restrict__ Wp,
                                                  const float* __restrict__ Vt,
                                                  const float* __restrict__ cvec,
                                                  float* __restrict__ out) {
    __shared__ float lds[IN_LEN * RANK];
    const int tid = threadIdx.x;
    const int b = blockIdx.y;
    const int c0 = 2 * (blockIdx.x * 256 + tid);
    const bool active = (c0 < CHANNELS);

    {
        const float4* src = (const float4*)Wp;
        float4* dst = (float4*)lds;
        for (int i = tid; i < IN_LEN * RANK / 4; i += 256) dst[i] = src[i];
    }
    __syncthreads();

    float acc0[RANK], acc1[RANK];
    float S0 = 0.f, S1 = 0.f, mean0 = 0.f, mean1 = 0.f;

    if (active) {
        #pragma unroll
        for (int r = 0; r < RANK; ++r) { acc0[r] = 0.f; acc1[r] = 0.f; }
        const float* xp = x + (size_t)b * (SEQ_LEN * CHANNELS) + c0;
        #pragma unroll 2
        for (int n = 0; n < IN_LEN; ++n) {
            float2 a0 = *(const float2*)(xp + (2 * n)     * CHANNELS);
            float2 a1 = *(const float2*)(xp + (2 * n + 1) * CHANNELS);
            float p0 = a0.x + a1.x;
            float p1 = a0.y + a1.y;
            S0 += p0; S1 += p1;
            const float4* w = (const float4*)(lds + n * RANK);
            #pragma unroll
            for (int q = 0; q < 8; ++q) {
                float4 wv = w[q];
                acc0[4*q+0] = fmaf(p0, wv.x, acc0[4*q+0]);
                acc1[4*q+0] = fmaf(p1, wv.x, acc1[4*q+0]);
                acc0[4*q+1] = fmaf(p0, wv.y, acc0[4*q+1]);
                acc1[4*q+1] = fmaf(p1, wv.y, acc1[4*q+1]);
                acc0[4*q+2] = fmaf(p0, wv.z, acc0[4*q+2]);
                acc1[4*q+2] = fmaf(p1, wv.z, acc1[4*q+2]);
                acc0[4*q+3] = fmaf(p0, wv.w, acc0[4*q+3]);
                acc1[4*q+3] = fmaf(p1, wv.w, acc1[4*q+3]);
            }
        }
        float g0 = -S0 * (1.0f / 360.0f) * 0.037267799624996496f;
        float g1 = -S1 * (1.0f / 360.0f) * 0.037267799624996496f;
        #pragma unroll
        for (int q = 0; q < 8; ++q) {
            float4 a4 = ((const float4*)A)[q];
            acc0[4*q+0] = fmaf(g0, a4.x, acc0[4*q+0]);
            acc1[4*q+0] = fmaf(g1, a4.x, acc1[4*q+0]);
            acc0[4*q+1] = fmaf(g0, a4.y, acc0[4*q+1]);
            acc1[4*q+1] = fmaf(g1, a4.y, acc1[4*q+1]);
            acc0[4*q+2] = fmaf(g0, a4.z, acc0[4*q+2]);
            acc1[4*q+2] = fmaf(g1, a4.z, acc1[4*q+2]);
            acc0[4*q+3] = fmaf(g0, a4.w, acc0[4*q+3]);
            acc1[4*q+3] = fmaf(g1, a4.w, acc1[4*q+3]);
        }
        mean0 = S0 * (1.0f / 720.0f);
        mean1 = S1 * (1.0f / 720.0f);
    }
    __syncthreads();

    {
        const float4* src = (const float4*)Vt;
        float4* dst = (float4*)lds;
        for (int i = tid; i < PRED_LEN * RANK / 4; i += 256) dst[i] = src[i];
        const float4* src2 = (const float4*)cvec;
        float4* dst2 = (float4*)(lds + PRED_LEN * RANK);
        for (int i = tid; i < PRED_LEN / 4; i += 256) dst2[i] = src2[i];
    }
    __syncthreads();

    if (active) {
        float* op = out + (size_t)b * (PRED_LEN * CHANNELS) + c0;
        for (int n = 0; n < PRED_LEN; ++n) {
            const float4* v = (const float4*)(lds + n * RANK);
            float o0a=0.f,o0b=0.f,o0c=0.f,o0d=0.f;
            float o1a=0.f,o1b=0.f,o1c=0.f,o1d=0.f;
            #pragma unroll
            for (int q = 0; q < 8; ++q) {
                float4 vv = v[q];
                o0a = fmaf(acc0[4*q+0], vv.x, o0a);
                o1a = fmaf(acc1[4*q+0], vv.x, o1a);
                o0b = fmaf(acc0[4*q+1], vv.y, o0b);
                o1b = fmaf(acc1[4*q+1], vv.y, o1b);
                o0c = fmaf(acc0[4*q+2], vv.z, o0c);
                o1c = fmaf(acc1[4*q+2], vv.z, o1c);
                o0d = fmaf(acc0[4*q+3], vv.w, o0d);
                o1d = fmaf(acc1[4*q+3], vv.w, o1d);
            }
            float cvn = lds[PRED_LEN * RANK + n];
            float2 o;
            o.x = (o0a + o0b) + (o0c + o0d) + cvn + mean0;
            o.y = (o1a + o1b) + (o1c + o1d) + cvn + mean1;
            *(float2*)(op + n * CHANNELS) = o;
        }
    }
}

// ---------------- launcher ---------------------------------------------------

extern "C" void kernel_launch(void* const* d_in, const int* in_sizes, int n_in,
                              void* d_out, int out_size, void* d_ws, size_t ws_size,
                              hipStream_t stream) {
    (void)in_sizes; (void)n_in; (void)out_size;
    const float* x    = (const float*)d_in[0];
    const float* A    = (const float*)d_in[1];
    const float* B    = (const float*)d_in[2];
    const float* bias = (const float*)d_in[3];
    float* out = (float*)d_out;
    float* ws  = (float*)d_ws;

    float* Wp   = ws + WS_WP;
    float* Vt   = ws + WS_VT;
    float* cvec = ws + WS_CVEC;

    k_prep<<<dim3(89), dim3(256), 0, stream>>>(A, B, bias, Wp, Vt, cvec);

    if (ws_size >= (size_t)WS_TOTAL * sizeof(float)) {
        float* wsT = ws + WS_T;
        float* wsS = ws + WS_S;
        k_partial<<<dim3(4, BATCH), dim3(256), 0, stream>>>(x, Wp, wsT, wsS);
        k_final<<<dim3(4, BATCH), dim3(256), 0, stream>>>(A, Vt, cvec, wsT, wsS, out);
    } else {
        k_fused<<<dim3(2, BATCH), dim3(256), 0, stream>>>(x, A, Wp, Vt, cvec, out);
    }
}

// Round 8
// 298.779 us; speedup vs baseline: 5.7894x; 5.7894x over previous
//
#include <hip/hip_runtime.h>
#include <math.h>

#define SEQ_LEN   720
#define IN_LEN    360
#define PRED_LEN  336
#define CHANNELS  862
#define RANK      32
#define BATCH     256

typedef _Float16 h2 __attribute__((ext_vector_type(2)));

// ws float offsets
#define WS_WP    0        // Wp  [360][32] fp32
#define WS_VT    11520    // Vt  [336][32] fp32
#define WS_CVEC  22272    // cvec[336] fp32
#define WS_WH    22608    // packed W: u32[180*32]  word[np*32+r] = (W[2np][r], W[2np+1][r])
#define WS_VH    28368    // packed V: u32[336*16]  word[n*16+q]  = (V[n][2q],  V[n][2q+1])
// total 33744 floats = 135 KB (ws >= 58 MB verified in round 6)

__device__ __forceinline__ float fdot2w(h2 a, h2 b, float c) {
#if __has_builtin(__builtin_amdgcn_fdot2)
    return __builtin_amdgcn_fdot2(a, b, c, false);
#else
    return fmaf((float)a[0], (float)b[0], fmaf((float)a[1], (float)b[1], c));
#endif
}
// cvt_pkrtz returns __fp16x2; bit-cast to our h2 (_Float16x2) — same layout
__device__ __forceinline__ h2 pkrtz(float a, float b) {
    return __builtin_bit_cast(h2, __builtin_amdgcn_cvt_pkrtz(a, b));
}
#define BC(u) __builtin_bit_cast(h2, (u))

// ---------------- prep: fold DCT/IDCT into Wp, Vt, cvec ----------------------
__global__ __launch_bounds__(256) void k_prep(const float* __restrict__ A,
                                              const float* __restrict__ B,
                                              const float* __restrict__ bias,
                                              float* __restrict__ Wp,
                                              float* __restrict__ Vt,
                                              float* __restrict__ cvec) {
    __shared__ float sbuf[IN_LEN * RANK];
    int blk = blockIdx.x;
    if (blk < 45) {
        for (int i = threadIdx.x; i < IN_LEN * RANK; i += 256) sbuf[i] = A[i];
        __syncthreads();
        int idx = blk * 256 + threadIdx.x;           // 45*256 == 11520
        int n = idx >> 5, r = idx & 31;
        int step = 2 * n + 1, m = 0;                 // k*(2n+1) mod 1440
        float sum = 0.f;
        for (int k = 0; k < IN_LEN; ++k) {
            float coef = (k == 0) ? 0.05270462766947299f    // 1/sqrt(360)
                                  : 0.07453559924999299f;   // 2/sqrt(720)
            float d = coef * cospif((float)m * (1.0f / 720.0f));
            sum = fmaf(d, sbuf[k * RANK + r], sum);
            m += step; if (m >= 1440) m -= 1440;
        }
        Wp[idx] = sum * 0.0019641855032960957f;      // (1/sqrt2)/360
    } else if (blk < 87) {
        for (int i = threadIdx.x; i < PRED_LEN * RANK; i += 256) {
            int r = i / PRED_LEN, k = i - r * PRED_LEN;
            sbuf[k * RANK + r] = B[i];               // B^T -> [k][r]
        }
        __syncthreads();
        int idx = (blk - 45) * 256 + threadIdx.x;    // 42*256 == 10752
        int n = idx >> 5, r = idx & 31;
        int step = 2 * n + 1, m = 0;                 // k*(2n+1) mod 1344
        float sum = 0.f;
        for (int k = 0; k < PRED_LEN; ++k) {
            float mk = cospif((float)m * (1.0f / 672.0f));
            if (k == 0) mk *= 0.5f;
            sum = fmaf(mk, sbuf[k * RANK + r], sum);
            m += step; if (m >= 1344) m -= 1344;
        }
        Vt[idx] = sum * (1.0f / 336.0f);
    } else {
        int n = (blk - 87) * 256 + threadIdx.x;
        if (n < PRED_LEN) {
            int step = 2 * n + 1, m = 0;
            float sum = 0.f;
            for (int k = 0; k < PRED_LEN; ++k) {
                float mk = cospif((float)m * (1.0f / 672.0f));
                if (k == 0) mk *= 0.5f;
                sum = fmaf(mk, bias[k], sum);
                m += step; if (m >= 1344) m -= 1344;
            }
            cvec[n] = sum * (1.0f / 336.0f);
        }
    }
}

// ---------------- pack fp32 weights into paired fp16 -------------------------
__global__ __launch_bounds__(256) void k_pack(const float* __restrict__ Wp,
                                              const float* __restrict__ Vt,
                                              unsigned* __restrict__ Wh,
                                              unsigned* __restrict__ Vh) {
    int idx = blockIdx.x * 256 + threadIdx.x;        // 44*256 = 11264 >= 11136
    if (idx < 5760) {
        int np = idx >> 5, r = idx & 31;
        h2 v = pkrtz(Wp[(2 * np) * RANK + r], Wp[(2 * np + 1) * RANK + r]);
        Wh[idx] = __builtin_bit_cast(unsigned, v);
    } else if (idx < 5760 + 5376) {
        int j = idx - 5760;
        int n = j >> 4, q = j & 15;
        h2 v = pkrtz(Vt[n * RANK + 2 * q], Vt[n * RANK + 2 * q + 1]);
        Vh[j] = __builtin_bit_cast(unsigned, v);
    }
}

// ---------------- fused main kernel ------------------------------------------
// cpt=2, grid (2, BATCH), 256 thr (R2-proven shape). fp16-paired weights in
// LDS: phase-1 reads 1440 ds_read_b128/wave (half of fp32), phase-2 1344.
// v_dot2_f32_f16 = 2 MACs/inst. Mean/bias path fp32 exact.
__global__ __launch_bounds__(256) void k_main(const float* __restrict__ x,
                                              const float* __restrict__ A,
                                              const unsigned* __restrict__ Wh,
                                              const unsigned* __restrict__ Vh,
                                              const float* __restrict__ cvec,
                                              float* __restrict__ out) {
    __shared__ uint4 lds4[1440];                     // 23040 B (ph1: W; ph2: V+cvec)
    unsigned* ldsu = (unsigned*)lds4;
    const int tid = threadIdx.x;
    const int b = blockIdx.y;
    const int c0 = 2 * (blockIdx.x * 256 + tid);
    const bool active = (c0 < CHANNELS);

    // ---- stage packed W ----
    {
        const uint4* s = (const uint4*)Wh;
        for (int i = tid; i < 1440; i += 256) lds4[i] = s[i];
    }
    __syncthreads();

    float acc0[RANK], acc1[RANK];
    #pragma unroll
    for (int r = 0; r < RANK; ++r) { acc0[r] = 0.f; acc1[r] = 0.f; }
    float S0 = 0.f, S1 = 0.f, mean0 = 0.f, mean1 = 0.f;
    h2 th0[16], th1[16];

    if (active) {
        const float* xp = x + (size_t)b * (SEQ_LEN * CHANNELS) + c0;

        // body bd covers np = 2bd, 2bd+1  (x rows 8bd .. 8bd+7)
        float2 bufA[8], bufB[8];
        #define LOADB(BUF, BD) { const float* p_ = xp + (size_t)(BD) * (8 * CHANNELS); \
            _Pragma("unroll") \
            for (int j_ = 0; j_ < 8; ++j_) BUF[j_] = *(const float2*)(p_ + j_ * CHANNELS); }

        // one n-pair: rows BUF[4S..4S+3]; W words at wr[8S..8S+7]
        #define NPBODY(BUF, S) { \
            float pe0 = BUF[4*S+0].x + BUF[4*S+1].x; \
            float pe1 = BUF[4*S+0].y + BUF[4*S+1].y; \
            float po0 = BUF[4*S+2].x + BUF[4*S+3].x; \
            float po1 = BUF[4*S+2].y + BUF[4*S+3].y; \
            S0 += pe0 + po0; S1 += pe1 + po1; \
            h2 P0 = pkrtz(pe0, po0); \
            h2 P1 = pkrtz(pe1, po1); \
            _Pragma("unroll") \
            for (int q_ = 0; q_ < 8; ++q_) { \
                uint4 wv = wr[8*S + q_]; \
                acc0[4*q_+0] = fdot2w(P0, BC(wv.x), acc0[4*q_+0]); \
                acc1[4*q_+0] = fdot2w(P1, BC(wv.x), acc1[4*q_+0]); \
                acc0[4*q_+1] = fdot2w(P0, BC(wv.y), acc0[4*q_+1]); \
                acc1[4*q_+1] = fdot2w(P1, BC(wv.y), acc1[4*q_+1]); \
                acc0[4*q_+2] = fdot2w(P0, BC(wv.z), acc0[4*q_+2]); \
                acc1[4*q_+2] = fdot2w(P1, BC(wv.z), acc1[4*q_+2]); \
                acc0[4*q_+3] = fdot2w(P0, BC(wv.w), acc0[4*q_+3]); \
                acc1[4*q_+3] = fdot2w(P1, BC(wv.w), acc1[4*q_+3]); \
            } }

        #define BODY(BUF, BD) { const uint4* wr = lds4 + 16 * (BD); \
            NPBODY(BUF, 0); NPBODY(BUF, 1); }

        LOADB(bufA, 0)
        for (int it = 0; it < 45; ++it) {
            LOADB(bufB, 2 * it + 1)
            BODY(bufA, 2 * it)
            if (it < 44) LOADB(bufA, 2 * it + 2)
            BODY(bufB, 2 * it + 1)
        }
        #undef BODY
        #undef NPBODY
        #undef LOADB

        // finalize: csw[r] = A[0][r]/sqrt(720);  t -= (S/360)*csw  (fp32 exact)
        const float k360 = (1.0f / 360.0f) * 0.037267799624996496f;
        float g0 = -S0 * k360, g1 = -S1 * k360;
        #pragma unroll
        for (int q = 0; q < 8; ++q) {
            float4 a4 = ((const float4*)A)[q];       // A[0][0..31], uniform, L2-hot
            acc0[4*q+0] = fmaf(g0, a4.x, acc0[4*q+0]);
            acc1[4*q+0] = fmaf(g1, a4.x, acc1[4*q+0]);
            acc0[4*q+1] = fmaf(g0, a4.y, acc0[4*q+1]);
            acc1[4*q+1] = fmaf(g1, a4.y, acc1[4*q+1]);
            acc0[4*q+2] = fmaf(g0, a4.z, acc0[4*q+2]);
            acc1[4*q+2] = fmaf(g1, a4.z, acc1[4*q+2]);
            acc0[4*q+3] = fmaf(g0, a4.w, acc0[4*q+3]);
            acc1[4*q+3] = fmaf(g1, a4.w, acc1[4*q+3]);
        }
        mean0 = S0 * (1.0f / 720.0f);
        mean1 = S1 * (1.0f / 720.0f);

        // pack t to fp16 pairs for phase 2
        #pragma unroll
        for (int u = 0; u < 16; ++u) {
            th0[u] = pkrtz(acc0[2*u], acc0[2*u+1]);
            th1[u] = pkrtz(acc1[2*u], acc1[2*u+1]);
        }
    }
    __syncthreads();                                 // phase-1 LDS reads done

    // ---- re-stage: packed V + fp32 cvec ----
    {
        const uint4* s = (const uint4*)Vh;
        for (int i = tid; i < 1344; i += 256) lds4[i] = s[i];
        for (int i = tid; i < PRED_LEN; i += 256)
            ldsu[5376 + i] = __float_as_uint(cvec[i]);
    }
    __syncthreads();

    // ---- phase 2: out[b][n][c] = t . V[n][:] + cvec[n] + mean ----
    if (active) {
        float* op = out + (size_t)b * (PRED_LEN * CHANNELS) + c0;
        #pragma unroll 2
        for (int n = 0; n < PRED_LEN; ++n) {
            const uint4* vr = lds4 + n * 4;
            float oA0 = 0.f, oB0 = 0.f, oA1 = 0.f, oB1 = 0.f;
            #pragma unroll
            for (int q = 0; q < 4; ++q) {
                uint4 v = vr[q];
                oA0 = fdot2w(th0[4*q+0], BC(v.x), oA0);
                oA1 = fdot2w(th1[4*q+0], BC(v.x), oA1);
                oB0 = fdot2w(th0[4*q+1], BC(v.y), oB0);
                oB1 = fdot2w(th1[4*q+1], BC(v.y), oB1);
                oA0 = fdot2w(th0[4*q+2], BC(v.z), oA0);
                oA1 = fdot2w(th1[4*q+2], BC(v.z), oA1);
                oB0 = fdot2w(th0[4*q+3], BC(v.w), oB0);
                oB1 = fdot2w(th1[4*q+3], BC(v.w), oB1);
            }
            float cvn = __uint_as_float(ldsu[5376 + n]);
            float2 o;
            o.x = (oA0 + oB0) + cvn + mean0;
            o.y = (oA1 + oB1) + cvn + mean1;
            *(float2*)op = o;
            op += CHANNELS;
        }
    }
}

// ---------------- launcher ---------------------------------------------------

extern "C" void kernel_launch(void* const* d_in, const int* in_sizes, int n_in,
                              void* d_out, int out_size, void* d_ws, size_t ws_size,
                              hipStream_t stream) {
    (void)in_sizes; (void)n_in; (void)out_size; (void)ws_size;
    const float* x    = (const float*)d_in[0];
    const float* A    = (const float*)d_in[1];
    const float* B    = (const float*)d_in[2];
    const float* bias = (const float*)d_in[3];
    float* out = (float*)d_out;
    float* ws  = (float*)d_ws;

    float*    Wp   = ws + WS_WP;
    float*    Vt   = ws + WS_VT;
    float*    cvec = ws + WS_CVEC;
    unsigned* Wh   = (unsigned*)(ws + WS_WH);
    unsigned* Vh   = (unsigned*)(ws + WS_VH);

    k_prep<<<dim3(89), dim3(256), 0, stream>>>(A, B, bias, Wp, Vt, cvec);
    k_pack<<<dim3(44), dim3(256), 0, stream>>>(Wp, Vt, Wh, Vh);
    k_main<<<dim3(2, BATCH), dim3(256), 0, stream>>>(x, A, Wh, Vh, cvec, out);
}